// Round 12
// baseline (330.664 us; speedup 1.0000x reference)
//
#include <hip/hip_runtime.h>
#include <hip/hip_bf16.h>
#include <math.h>

// ViT encoder block, bf16-MFMA. Round 12 (from verified 296.7us round-11):
//  - NEW gemm_bt8: 8-wave (512-thr) 128^2 tile, per-wave 64x32 output.
//    Halves per-wave registers (acc 32 vs 64) -> __launch_bounds__(512,6)
//    -> 6 waves/SIMD (24 waves/CU vs 16). Applied ONLY to the two 73-us
//    pillars: fc1 (EPI1) and fc2 split-K partials (EPI6). Revertible.
//  - everything else identical to round 11.

#define C_DIM   768
#define SEQ     577
#define BATCH   16
#define NHEAD   12
#define DHEAD   64
#define MREAL   (BATCH*SEQ)     /* 9232 */
#define MPAD    9472            /* 74*128 */
#define HID     3072
#define QKW     1536
#define NKV     640
#define QSCALE  0.1803368801111204f  /* Dh^-0.5 * log2(e) */

typedef __hip_bfloat16 bf16;
typedef __attribute__((ext_vector_type(8))) short v8s;
typedef __attribute__((ext_vector_type(4))) float v4f;

static __device__ __forceinline__ bf16 f2b(float f){ return __float2bfloat16(f); }
static __device__ __forceinline__ float us2f(unsigned short u){
  union{ float f; unsigned int i; } x; x.i = ((unsigned int)u)<<16; return x.f;
}
static __device__ __forceinline__ short f2s(float f){
  bf16 t = __float2bfloat16(f); return *(short*)&t;
}
static __device__ __forceinline__ float gelu_fast(float x){
  float z2 = 2.302585092994046f * x * (1.f + 0.044715f*x*x);
  return x / (1.f + exp2f(-z2));
}

// ---------------- merged weight transpose+cast ----------------
__global__ __launch_bounds__(256) void k_transpose_all(
    const float* __restrict__ qkvw, const float* __restrict__ projw,
    const float* __restrict__ fc1w, const float* __restrict__ fc2w,
    bf16* __restrict__ qkvT, bf16* __restrict__ projT,
    bf16* __restrict__ fc1T, bf16* __restrict__ fc2T)
{
  int id = blockIdx.x;
  const float* src; bf16* dst; int R, C, nx;
  if (id < 432)      { src=qkvw; dst=qkvT; R=768;  C=2304; nx=36; }
  else if (id < 576) { id-=432; src=projw; dst=projT; R=768;  C=768;  nx=12; }
  else if (id < 1152){ id-=576; src=fc1w;  dst=fc1T;  R=768;  C=3072; nx=48; }
  else               { id-=1152; src=fc2w; dst=fc2T;  R=3072; C=768;  nx=12; }
  const int tr = (id/nx)*64, tc = (id%nx)*64;

  __shared__ float s[64][65];
  const int t = threadIdx.x;
  const int lr = t >> 4, lc4 = t & 15;
  #pragma unroll
  for (int i=0;i<4;i++){
    int r = lr + i*16;
    float4 v = *(const float4*)(src + (size_t)(tr+r)*C + tc + lc4*4);
    s[r][lc4*4+0]=v.x; s[r][lc4*4+1]=v.y; s[r][lc4*4+2]=v.z; s[r][lc4*4+3]=v.w;
  }
  __syncthreads();
  const int c = t >> 2, seg = t & 3;
  alignas(16) bf16 tmp[16];
  #pragma unroll
  for (int j=0;j<16;j++) tmp[j] = f2b(s[seg*16+j][c]);
  bf16* dp = dst + (size_t)(tc+c)*R + tr + seg*16;
  *(uint4*)dp       = *(uint4*)tmp;
  *(uint4*)(dp + 8) = *(uint4*)(tmp + 8);
}

__global__ __launch_bounds__(256) void k_layernorm(
    const float* __restrict__ in, const float* __restrict__ g,
    const float* __restrict__ b, bf16* __restrict__ o)
{
  int row = blockIdx.x, tid = threadIdx.x;
  size_t base = (size_t)row*C_DIM;
  if (row >= MREAL){
    #pragma unroll
    for (int j=0;j<3;j++) o[base + tid + j*256] = f2b(0.f);
    return;
  }
  float v[3], s=0.f, ss=0.f;
  #pragma unroll
  for (int j=0;j<3;j++){ v[j] = in[base + tid + j*256]; s += v[j]; ss += v[j]*v[j]; }
  #pragma unroll
  for (int off=32; off>0; off>>=1){ s += __shfl_xor(s,off); ss += __shfl_xor(ss,off); }
  __shared__ float red[8];
  int wv = tid>>6;
  if ((tid&63)==0){ red[wv] = s; red[4+wv] = ss; }
  __syncthreads();
  float S  = red[0]+red[1]+red[2]+red[3];
  float SS = red[4]+red[5]+red[6]+red[7];
  float mu   = S*(1.f/C_DIM);
  float rstd = rsqrtf(SS*(1.f/C_DIM) - mu*mu + 1e-5f);
  #pragma unroll
  for (int j=0;j<3;j++){
    int c = tid + j*256;
    o[base+c] = f2b((v[j]-mu)*rstd*g[c] + b[c]);
  }
}

// proj split-K reduce fused with LN2
__global__ __launch_bounds__(256) void k_reduce2_ln(
    const bf16* __restrict__ P, const float* __restrict__ bias,
    const float* __restrict__ resid, float* __restrict__ out,
    const float* __restrict__ g, const float* __restrict__ bln,
    bf16* __restrict__ xn2)
{
  int row = blockIdx.x, tid = threadIdx.x;
  size_t base = (size_t)row*C_DIM;
  if (row >= MREAL){
    #pragma unroll
    for (int j=0;j<3;j++) xn2[base + tid + j*256] = f2b(0.f);
    return;
  }
  const unsigned short* P0 = (const unsigned short*)P;
  const unsigned short* P1 = P0 + (size_t)MPAD*C_DIM;
  float v[3], s=0.f, ss=0.f;
  #pragma unroll
  for (int j=0;j<3;j++){
    int c = tid + j*256;
    size_t idx = base + c;
    float val = us2f(P0[idx]) + us2f(P1[idx]) + bias[c] + resid[idx];
    out[idx] = val; v[j] = val; s += val; ss += val*val;
  }
  #pragma unroll
  for (int off=32; off>0; off>>=1){ s += __shfl_xor(s,off); ss += __shfl_xor(ss,off); }
  __shared__ float red[8];
  int wv = tid>>6;
  if ((tid&63)==0){ red[wv] = s; red[4+wv] = ss; }
  __syncthreads();
  float S  = red[0]+red[1]+red[2]+red[3];
  float SS = red[4]+red[5]+red[6]+red[7];
  float mu   = S*(1.f/C_DIM);
  float rstd = rsqrtf(SS*(1.f/C_DIM) - mu*mu + 1e-5f);
  #pragma unroll
  for (int j=0;j<3;j++){
    int c = tid + j*256;
    xn2[base+c] = f2b((v[j]-mu)*rstd*g[c] + bln[c]);
  }
}

// fc2 split-K=2 reduce
__global__ __launch_bounds__(256) void k_reduce2(
    const bf16* __restrict__ P, const float* __restrict__ bias,
    const float* __restrict__ resid, float* __restrict__ out)
{
  size_t i = ((size_t)blockIdx.x*256 + threadIdx.x)*8;
  int c = (int)(i % C_DIM);
  v8s p0 = *(const v8s*)(P + i);
  v8s p1 = *(const v8s*)(P + (size_t)MPAD*C_DIM + i);
  float r[8];
  #pragma unroll
  for (int j=0;j<8;j++) r[j] = resid[i+j];
  #pragma unroll
  for (int j=0;j<8;j++)
    out[i+j] = us2f((unsigned short)p0[j]) + us2f((unsigned short)p1[j])
             + bias[c+j] + r[j];
}

// ---------------- fused flash attention (verified) ----------------
__global__ __launch_bounds__(256, 3) void k_flash(
    const bf16* __restrict__ qk, const bf16* __restrict__ VtAll,
    bf16* __restrict__ y)
{
  __shared__ alignas(16) bf16 sK[2][64*64];
  __shared__ alignas(16) bf16 sV[2][64*64];
  __shared__ alignas(16) bf16 sP[4][16*72];

  const int tid = threadIdx.x;
  const int wave = tid>>6, lane = tid&63;
  const int r16 = lane&15, kg = lane>>4;

  const int id = blockIdx.x;
  const int swz = (id&7)*240 + (id>>3);
  const int hh = swz/10, qt = swz - hh*10;
  const int b_ = hh/NHEAD, h_ = hh - b_*NHEAD;

  const int qrow = b_*SEQ + qt*64 + wave*16 + r16;
  v8s qf[2];
  qf[0] = *(const v8s*)(qk + (size_t)qrow*QKW + h_*DHEAD + kg*8);
  qf[1] = *(const v8s*)(qk + (size_t)qrow*QKW + h_*DHEAD + 32 + kg*8);

  auto stage = [&](int kt, int buf){
    #pragma unroll
    for (int i=0;i<2;i++){
      int chunk = i*256 + tid;
      int row = chunk>>3, ch = chunk&7;
      int sc = ch ^ (row&7);
      const bf16* gk = qk + (size_t)(b_*SEQ + kt*64 + row)*QKW
                          + C_DIM + h_*DHEAD + sc*8;
      const bf16* gv = VtAll + (size_t)(b_*C_DIM + h_*DHEAD + row)*NKV
                             + kt*64 + sc*8;
      __builtin_amdgcn_global_load_lds(
          (const __attribute__((address_space(1))) void*)gk,
          (__attribute__((address_space(3))) void*)((char*)&sK[buf][0] + i*4096 + wave*1024),
          16, 0, 0);
      __builtin_amdgcn_global_load_lds(
          (const __attribute__((address_space(1))) void*)gv,
          (__attribute__((address_space(3))) void*)((char*)&sV[buf][0] + i*4096 + wave*1024),
          16, 0, 0);
    }
  };

  float m_run = -1e30f, l_run = 0.f;
  v4f zero4 = {0.f,0.f,0.f,0.f};
  v4f o[4] = {zero4, zero4, zero4, zero4};

  stage(0, 0);
  for (int kt=0; kt<10; ++kt){
    __syncthreads();
    if (kt < 9) stage(kt+1, (kt+1)&1);
    const bf16* Kt = &sK[kt&1][0];
    const bf16* Vt = &sV[kt&1][0];

    v4f sfr[4] = {zero4, zero4, zero4, zero4};
    #pragma unroll
    for (int ks=0; ks<2; ++ks){
      #pragma unroll
      for (int m=0;m<4;m++){
        int key = m*16 + r16;
        v8s kf = *(const v8s*)(Kt + key*64 + (((ks*4+kg) ^ (key&7))*8));
        sfr[m] = __builtin_amdgcn_mfma_f32_16x16x32_bf16(kf, qf[ks], sfr[m], 0, 0, 0);
      }
    }

    if (kt == 9){
      #pragma unroll
      for (int m=0;m<4;m++)
        #pragma unroll
        for (int gg=0; gg<4; ++gg){
          int kb = 576 + m*16 + kg*4 + gg;
          if (kb >= SEQ) sfr[m][gg] = -1e30f;
        }
    }

    float tmax = -1e30f;
    #pragma unroll
    for (int m=0;m<4;m++)
      #pragma unroll
      for (int gg=0; gg<4; ++gg) tmax = fmaxf(tmax, sfr[m][gg]);
    tmax = fmaxf(tmax, __shfl_xor(tmax, 16));
    tmax = fmaxf(tmax, __shfl_xor(tmax, 32));
    float mn  = fmaxf(m_run, tmax);
    float scl = exp2f(m_run - mn);
    float ps  = 0.f;
    #pragma unroll
    for (int m=0;m<4;m++)
      #pragma unroll
      for (int gg=0; gg<4; ++gg){
        float pv = exp2f(sfr[m][gg] - mn);
        sfr[m][gg] = pv; ps += pv;
      }
    ps += __shfl_xor(ps, 16);
    ps += __shfl_xor(ps, 32);
    l_run = l_run*scl + ps;
    m_run = mn;
    #pragma unroll
    for (int mf=0; mf<4; ++mf) o[mf] *= scl;

    bf16* Pw = &sP[wave][0];
    #pragma unroll
    for (int m=0;m<4;m++){
      short4 w;
      w.x = f2s(sfr[m][0]); w.y = f2s(sfr[m][1]);
      w.z = f2s(sfr[m][2]); w.w = f2s(sfr[m][3]);
      *(short4*)(Pw + r16*72 + m*16 + kg*4) = w;
    }
    asm volatile("s_waitcnt lgkmcnt(0)" ::: "memory");
    v8s pb0 = *(const v8s*)(Pw + r16*72 + kg*8);
    v8s pb1 = *(const v8s*)(Pw + r16*72 + 32 + kg*8);
    #pragma unroll
    for (int mf=0; mf<4; ++mf){
      int d = mf*16 + r16;
      v8s v0 = *(const v8s*)(Vt + d*64 + ((kg     ^ (d&7))*8));
      v8s v1 = *(const v8s*)(Vt + d*64 + (((4+kg) ^ (d&7))*8));
      o[mf] = __builtin_amdgcn_mfma_f32_16x16x32_bf16(v0, pb0, o[mf], 0, 0, 0);
      o[mf] = __builtin_amdgcn_mfma_f32_16x16x32_bf16(v1, pb1, o[mf], 0, 0, 0);
    }
  }

  const int qg = qt*64 + wave*16 + r16;
  if (qg < SEQ){
    float inv = 1.f / l_run;
    #pragma unroll
    for (int mf=0; mf<4; ++mf){
      short4 w;
      w.x = f2s(o[mf][0]*inv); w.y = f2s(o[mf][1]*inv);
      w.z = f2s(o[mf][2]*inv); w.w = f2s(o[mf][3]*inv);
      *(short4*)(y + (size_t)(b_*SEQ + qg)*C_DIM + h_*DHEAD + mf*16 + kg*4) = w;
    }
  }
}

// ---------------- MFMA GEMM 4-wave (verified): qk / Vt / proj partials ------
// EPI 0: qk (+bias, *QSCALE cols<768)   EPI 5: Vt transposed scatter (+bias)
// EPI 6: bf16 split-K partial (blockIdx.z = K-chunk)
template<int EPI>
__global__ __launch_bounds__(256, 4) void gemm_bt(
    const bf16* __restrict__ A, int lda,
    const bf16* __restrict__ BT, int ldb,
    void* Cv, int ldc,
    const float* __restrict__ bias,
    const float* resid,
    int K)
{
  __shared__ alignas(16) bf16 sA[128*64];
  __shared__ alignas(16) bf16 sB[128*64];
  const int tid  = threadIdx.x;
  const int wave = tid>>6, lane = tid&63;
  const int wr = wave>>1, wc = wave&1;
  const int r16 = lane&15, kg = lane>>4;

  int nx = gridDim.x, nwg = nx*gridDim.y;
  int id = blockIdx.y*nx + blockIdx.x;
  int qq = nwg>>3, r8 = nwg&7, xcd = id&7, j = id>>3;
  int swz = (xcd<r8 ? xcd*(qq+1) : r8*(qq+1) + (xcd-r8)*qq) + j;
  int mt = swz / nx, nt = swz % nx;

  int kb = 0;
  if constexpr (EPI==6) kb = blockIdx.z * K;

  v4f acc[4][4];
  v4f zero4 = {0.f,0.f,0.f,0.f};
  #pragma unroll
  for (int m=0;m<4;m++)
    #pragma unroll
    for (int n=0;n<4;n++) acc[m][n] = zero4;

  const int mrow0 = mt*128, ncol0 = nt*128;

  for (int kt=0; kt<K; kt+=64){
    #pragma unroll
    for (int i=0;i<4;i++){
      int ci = wave*4 + i;
      int q  = ci*64 + lane;
      int rr = q>>3;
      int cc = (q&7)*8;
      const bf16* ga = A  + (size_t)(mrow0+rr)*lda + (kb+kt+cc);
      const bf16* gb = BT + (size_t)(ncol0+rr)*ldb + (kb+kt+cc);
      __builtin_amdgcn_global_load_lds(
          (const __attribute__((address_space(1))) void*)ga,
          (__attribute__((address_space(3))) void*)((char*)sA + ci*1024), 16, 0, 0);
      __builtin_amdgcn_global_load_lds(
          (const __attribute__((address_space(1))) void*)gb,
          (__attribute__((address_space(3))) void*)((char*)sB + ci*1024), 16, 0, 0);
    }
    __syncthreads();
    #pragma unroll
    for (int ks=0; ks<2; ks++){
      v8s av[4], bv[4];
      #pragma unroll
      for (int m=0;m<4;m++)
        av[m] = *(const v8s*)(sA + (wr*64 + m*16 + r16)*64 + ks*32 + kg*8);
      #pragma unroll
      for (int n=0;n<4;n++)
        bv[n] = *(const v8s*)(sB + (wc*64 + n*16 + r16)*64 + ks*32 + kg*8);
      #pragma unroll
      for (int m=0;m<4;m++)
        #pragma unroll
        for (int n=0;n<4;n++)
          acc[m][n] = __builtin_amdgcn_mfma_f32_16x16x32_bf16(av[m], bv[n], acc[m][n], 0, 0, 0);
    }
    __syncthreads();
  }

  #pragma unroll
  for (int m=0;m<4;m++){
    #pragma unroll
    for (int n=0;n<4;n++){
      int col = ncol0 + wc*64 + n*16 + r16;
      #pragma unroll
      for (int gg=0; gg<4; gg++){
        int row = mrow0 + wr*64 + m*16 + kg*4 + gg;
        float v = acc[m][n][gg];
        if constexpr (EPI==0){
          float oo = v + bias[col];
          if (col < C_DIM) oo *= QSCALE;
          ((bf16*)Cv)[(size_t)row*ldc + col] = f2b(oo);
        } else if constexpr (EPI==5){
          int g = col;
          if (g < MREAL){
            int b = g / SEQ;
            int key = g - b*SEQ;
            ((bf16*)Cv)[((size_t)b*C_DIM + row)*NKV + key] = f2b(v + bias[row]);
          }
        } else { // EPI==6
          ((bf16*)Cv)[(size_t)blockIdx.z*MPAD*C_DIM + (size_t)row*ldc + col] = f2b(v);
        }
      }
    }
  }
}

// ---------------- gemm_bt8: 8-wave 128^2, per-wave 64x32 (fc1, fc2p) --------
// Waves 2(M) x 4(N). acc[4][2] = 32 VGPR; ~80 total -> 6 waves/SIMD.
// Same verified staging / LDS layout / fragment formulas as gemm_bt.
// EPI 1: fc1 (+bias, fast GELU)   EPI 6: bf16 split-K partial (z chunk)
template<int EPI>
__global__ __launch_bounds__(512, 6) void gemm_bt8(
    const bf16* __restrict__ A, int lda,
    const bf16* __restrict__ BT, int ldb,
    void* Cv, int ldc,
    const float* __restrict__ bias,
    int K)
{
  __shared__ alignas(16) bf16 sA[128*64];
  __shared__ alignas(16) bf16 sB[128*64];
  const int tid  = threadIdx.x;
  const int wave = tid>>6, lane = tid&63;
  const int wr = wave>>2, wc = wave&3;   // 2 x 4
  const int r16 = lane&15, kg = lane>>4;

  int nx = gridDim.x, nwg = nx*gridDim.y;
  int id = blockIdx.y*nx + blockIdx.x;
  int qq = nwg>>3, r8 = nwg&7, xcd = id&7, j = id>>3;
  int swz = (xcd<r8 ? xcd*(qq+1) : r8*(qq+1) + (xcd-r8)*qq) + j;
  int mt = swz / nx, nt = swz % nx;

  int kb = 0;
  if constexpr (EPI==6) kb = blockIdx.z * K;

  v4f acc[4][2];
  v4f zero4 = {0.f,0.f,0.f,0.f};
  #pragma unroll
  for (int m=0;m<4;m++)
    #pragma unroll
    for (int n=0;n<2;n++) acc[m][n] = zero4;

  const int mrow0 = mt*128, ncol0 = nt*128;

  for (int kt=0; kt<K; kt+=64){
    #pragma unroll
    for (int i=0;i<2;i++){
      int ci = wave*2 + i;           // 16 one-KiB segments, 2 per wave
      int q  = ci*64 + lane;
      int rr = q>>3;
      int cc = (q&7)*8;
      const bf16* ga = A  + (size_t)(mrow0+rr)*lda + (kb+kt+cc);
      const bf16* gb = BT + (size_t)(ncol0+rr)*ldb + (kb+kt+cc);
      __builtin_amdgcn_global_load_lds(
          (const __attribute__((address_space(1))) void*)ga,
          (__attribute__((address_space(3))) void*)((char*)sA + ci*1024), 16, 0, 0);
      __builtin_amdgcn_global_load_lds(
          (const __attribute__((address_space(1))) void*)gb,
          (__attribute__((address_space(3))) void*)((char*)sB + ci*1024), 16, 0, 0);
    }
    __syncthreads();
    #pragma unroll
    for (int ks=0; ks<2; ks++){
      v8s av[4], bv[2];
      #pragma unroll
      for (int m=0;m<4;m++)
        av[m] = *(const v8s*)(sA + (wr*64 + m*16 + r16)*64 + ks*32 + kg*8);
      #pragma unroll
      for (int n=0;n<2;n++)
        bv[n] = *(const v8s*)(sB + (wc*32 + n*16 + r16)*64 + ks*32 + kg*8);
      #pragma unroll
      for (int m=0;m<4;m++)
        #pragma unroll
        for (int n=0;n<2;n++)
          acc[m][n] = __builtin_amdgcn_mfma_f32_16x16x32_bf16(av[m], bv[n], acc[m][n], 0, 0, 0);
    }
    __syncthreads();
  }

  #pragma unroll
  for (int m=0;m<4;m++){
    #pragma unroll
    for (int n=0;n<2;n++){
      int col = ncol0 + wc*32 + n*16 + r16;
      #pragma unroll
      for (int gg=0; gg<4; gg++){
        int row = mrow0 + wr*64 + m*16 + kg*4 + gg;
        float v = acc[m][n][gg];
        if constexpr (EPI==1){
          ((bf16*)Cv)[(size_t)row*ldc + col] = f2b(gelu_fast(v + bias[col]));
        } else { // EPI==6
          ((bf16*)Cv)[(size_t)blockIdx.z*MPAD*C_DIM + (size_t)row*ldc + col] = f2b(v);
        }
      }
    }
  }
}

// ---------------- launch ----------------

extern "C" void kernel_launch(void* const* d_in, const int* in_sizes, int n_in,
                              void* d_out, int out_size, void* d_ws, size_t ws_size,
                              hipStream_t stream)
{
  const float* x     = (const float*)d_in[0];
  const float* ln1g  = (const float*)d_in[1];
  const float* ln1b  = (const float*)d_in[2];
  const float* qkvw  = (const float*)d_in[3];
  const float* qkvb  = (const float*)d_in[4];
  const float* projw = (const float*)d_in[5];
  const float* projb = (const float*)d_in[6];
  const float* ln2g  = (const float*)d_in[7];
  const float* ln2b  = (const float*)d_in[8];
  const float* fc1w  = (const float*)d_in[9];
  const float* fc1b  = (const float*)d_in[10];
  const float* fc2w  = (const float*)d_in[11];
  const float* fc2b  = (const float*)d_in[12];
  float* out = (float*)d_out;

  char* p = (char*)d_ws;
  auto take = [&](size_t n){ char* r = p; p += (n + 255) & ~(size_t)255; return r; };
  bf16* qkvT = (bf16*)take((size_t)(3*C_DIM)*C_DIM*2);
  bf16* projT= (bf16*)take((size_t)C_DIM*C_DIM*2);
  bf16* fc1T = (bf16*)take((size_t)HID*C_DIM*2);
  bf16* fc2T = (bf16*)take((size_t)C_DIM*HID*2);
  bf16* xn   = (bf16*)take((size_t)MPAD*C_DIM*2);
  bf16* xn2  = (bf16*)take((size_t)MPAD*C_DIM*2);
  bf16* qk   = (bf16*)take((size_t)MPAD*QKW*2);   // later: split-K partials (2 x MPAD*C_DIM)
  bf16* y    = (bf16*)take((size_t)MPAD*C_DIM*2);
  bf16* h    = (bf16*)take((size_t)MPAD*HID*2);
  bf16* VtAll= (bf16*)take((size_t)(BATCH*C_DIM + 2*DHEAD)*NKV*2);
  bf16* P    = qk;  // partials overlay (qk dead after flash)

  k_transpose_all<<<1728, 256, 0, stream>>>(qkvw, projw, fc1w, fc2w,
                                            qkvT, projT, fc1T, fc2T);

  // LN1 -> xn
  k_layernorm<<<MPAD, 256, 0, stream>>>(x, ln1g, ln1b, xn);

  // qk = xn @ [Wq|Wk]^T + b
  gemm_bt<0><<<dim3(QKW/128, MPAD/128), 256, 0, stream>>>(
      xn, C_DIM, qkvT, C_DIM, qk, QKW, qkvb, nullptr, C_DIM);

  // VtAll = (xn @ Wv)^T + bv
  gemm_bt<5><<<dim3(MPAD/128, C_DIM/128), 256, 0, stream>>>(
      qkvT + (size_t)QKW*C_DIM, C_DIM, xn, C_DIM, VtAll, 0,
      qkvb + 2*C_DIM, nullptr, C_DIM);

  // fused flash attention -> y
  k_flash<<<1920, 256, 0, stream>>>(qk, VtAll, y);

  // proj split-K=2: partials, then fused reduce+LN2 (out, xn2)
  gemm_bt<6><<<dim3(C_DIM/128, MPAD/128, 2), 256, 0, stream>>>(
      y, C_DIM, projT, C_DIM, P, C_DIM, nullptr, nullptr, C_DIM/2);
  k_reduce2_ln<<<MPAD, 256, 0, stream>>>(P, projb, x, out, ln2g, ln2b, xn2);

  // h = gelu(xn2 @ fc1_w + b)  -- 8-wave variant
  gemm_bt8<1><<<dim3(HID/128, MPAD/128), 512, 0, stream>>>(
      xn2, C_DIM, fc1T, C_DIM, h, HID, fc1b, C_DIM);

  // fc2 split-K=2: partials (8-wave variant), then out = p0+p1+fc2b+out
  gemm_bt8<6><<<dim3(C_DIM/128, MPAD/128, 2), 512, 0, stream>>>(
      h, HID, fc2T, HID, P, C_DIM, nullptr, HID/2);
  k_reduce2<<<(MREAL*C_DIM)/(256*8), 256, 0, stream>>>(P, fc2b, out, out);
}

// Round 13
// 295.025 us; speedup vs baseline: 1.1208x; 1.1208x over previous
//
#include <hip/hip_runtime.h>
#include <hip/hip_bf16.h>
#include <math.h>

// ViT encoder block, bf16-MFMA. Round 13: exact revert to round-11 (296.7us),
// the verified optimum. gemm_bt8 refuted (VGPR squeezed to 36, +18us/dispatch;
// occupancy 54% yet slower -> the limiter is the barrier-drain structure, not
// wave residency). Ledger: 7 structural GEMM variants refuted; this is the
// verified plateau for the m97-structure at these short-K shapes.

#define C_DIM   768
#define SEQ     577
#define BATCH   16
#define NHEAD   12
#define DHEAD   64
#define MREAL   (BATCH*SEQ)     /* 9232 */
#define MPAD    9472            /* 74*128 */
#define HID     3072
#define QKW     1536
#define NKV     640
#define QSCALE  0.1803368801111204f  /* Dh^-0.5 * log2(e) */

typedef __hip_bfloat16 bf16;
typedef __attribute__((ext_vector_type(8))) short v8s;
typedef __attribute__((ext_vector_type(4))) float v4f;

static __device__ __forceinline__ bf16 f2b(float f){ return __float2bfloat16(f); }
static __device__ __forceinline__ float us2f(unsigned short u){
  union{ float f; unsigned int i; } x; x.i = ((unsigned int)u)<<16; return x.f;
}
static __device__ __forceinline__ short f2s(float f){
  bf16 t = __float2bfloat16(f); return *(short*)&t;
}
static __device__ __forceinline__ float gelu_fast(float x){
  float z2 = 2.302585092994046f * x * (1.f + 0.044715f*x*x);
  return x / (1.f + exp2f(-z2));
}

// ---------------- merged weight transpose+cast ----------------
__global__ __launch_bounds__(256) void k_transpose_all(
    const float* __restrict__ qkvw, const float* __restrict__ projw,
    const float* __restrict__ fc1w, const float* __restrict__ fc2w,
    bf16* __restrict__ qkvT, bf16* __restrict__ projT,
    bf16* __restrict__ fc1T, bf16* __restrict__ fc2T)
{
  int id = blockIdx.x;
  const float* src; bf16* dst; int R, C, nx;
  if (id < 432)      { src=qkvw; dst=qkvT; R=768;  C=2304; nx=36; }
  else if (id < 576) { id-=432; src=projw; dst=projT; R=768;  C=768;  nx=12; }
  else if (id < 1152){ id-=576; src=fc1w;  dst=fc1T;  R=768;  C=3072; nx=48; }
  else               { id-=1152; src=fc2w; dst=fc2T;  R=3072; C=768;  nx=12; }
  const int tr = (id/nx)*64, tc = (id%nx)*64;

  __shared__ float s[64][65];
  const int t = threadIdx.x;
  const int lr = t >> 4, lc4 = t & 15;
  #pragma unroll
  for (int i=0;i<4;i++){
    int r = lr + i*16;
    float4 v = *(const float4*)(src + (size_t)(tr+r)*C + tc + lc4*4);
    s[r][lc4*4+0]=v.x; s[r][lc4*4+1]=v.y; s[r][lc4*4+2]=v.z; s[r][lc4*4+3]=v.w;
  }
  __syncthreads();
  const int c = t >> 2, seg = t & 3;
  alignas(16) bf16 tmp[16];
  #pragma unroll
  for (int j=0;j<16;j++) tmp[j] = f2b(s[seg*16+j][c]);
  bf16* dp = dst + (size_t)(tc+c)*R + tr + seg*16;
  *(uint4*)dp       = *(uint4*)tmp;
  *(uint4*)(dp + 8) = *(uint4*)(tmp + 8);
}

__global__ __launch_bounds__(256) void k_layernorm(
    const float* __restrict__ in, const float* __restrict__ g,
    const float* __restrict__ b, bf16* __restrict__ o)
{
  int row = blockIdx.x, tid = threadIdx.x;
  size_t base = (size_t)row*C_DIM;
  if (row >= MREAL){
    #pragma unroll
    for (int j=0;j<3;j++) o[base + tid + j*256] = f2b(0.f);
    return;
  }
  float v[3], s=0.f, ss=0.f;
  #pragma unroll
  for (int j=0;j<3;j++){ v[j] = in[base + tid + j*256]; s += v[j]; ss += v[j]*v[j]; }
  #pragma unroll
  for (int off=32; off>0; off>>=1){ s += __shfl_xor(s,off); ss += __shfl_xor(ss,off); }
  __shared__ float red[8];
  int wv = tid>>6;
  if ((tid&63)==0){ red[wv] = s; red[4+wv] = ss; }
  __syncthreads();
  float S  = red[0]+red[1]+red[2]+red[3];
  float SS = red[4]+red[5]+red[6]+red[7];
  float mu   = S*(1.f/C_DIM);
  float rstd = rsqrtf(SS*(1.f/C_DIM) - mu*mu + 1e-5f);
  #pragma unroll
  for (int j=0;j<3;j++){
    int c = tid + j*256;
    o[base+c] = f2b((v[j]-mu)*rstd*g[c] + b[c]);
  }
}

// proj split-K reduce fused with LN2:
//   val = f32(P0)+f32(P1)+projb+x ; out=val ; xn2 = LN(val; g,bln)
__global__ __launch_bounds__(256) void k_reduce2_ln(
    const bf16* __restrict__ P, const float* __restrict__ bias,
    const float* __restrict__ resid, float* __restrict__ out,
    const float* __restrict__ g, const float* __restrict__ bln,
    bf16* __restrict__ xn2)
{
  int row = blockIdx.x, tid = threadIdx.x;
  size_t base = (size_t)row*C_DIM;
  if (row >= MREAL){
    #pragma unroll
    for (int j=0;j<3;j++) xn2[base + tid + j*256] = f2b(0.f);
    return;
  }
  const unsigned short* P0 = (const unsigned short*)P;
  const unsigned short* P1 = P0 + (size_t)MPAD*C_DIM;
  float v[3], s=0.f, ss=0.f;
  #pragma unroll
  for (int j=0;j<3;j++){
    int c = tid + j*256;
    size_t idx = base + c;
    float val = us2f(P0[idx]) + us2f(P1[idx]) + bias[c] + resid[idx];
    out[idx] = val; v[j] = val; s += val; ss += val*val;
  }
  #pragma unroll
  for (int off=32; off>0; off>>=1){ s += __shfl_xor(s,off); ss += __shfl_xor(ss,off); }
  __shared__ float red[8];
  int wv = tid>>6;
  if ((tid&63)==0){ red[wv] = s; red[4+wv] = ss; }
  __syncthreads();
  float S  = red[0]+red[1]+red[2]+red[3];
  float SS = red[4]+red[5]+red[6]+red[7];
  float mu   = S*(1.f/C_DIM);
  float rstd = rsqrtf(SS*(1.f/C_DIM) - mu*mu + 1e-5f);
  #pragma unroll
  for (int j=0;j<3;j++){
    int c = tid + j*256;
    xn2[base+c] = f2b((v[j]-mu)*rstd*g[c] + bln[c]);
  }
}

// fc2 split-K=2 reduce: out = f32(P0)+f32(P1)+bias+resid (resid aliases out)
__global__ __launch_bounds__(256) void k_reduce2(
    const bf16* __restrict__ P, const float* __restrict__ bias,
    const float* __restrict__ resid, float* __restrict__ out)
{
  size_t i = ((size_t)blockIdx.x*256 + threadIdx.x)*8;
  int c = (int)(i % C_DIM);
  v8s p0 = *(const v8s*)(P + i);
  v8s p1 = *(const v8s*)(P + (size_t)MPAD*C_DIM + i);
  float r[8];
  #pragma unroll
  for (int j=0;j<8;j++) r[j] = resid[i+j];
  #pragma unroll
  for (int j=0;j<8;j++)
    out[i+j] = us2f((unsigned short)p0[j]) + us2f((unsigned short)p1[j])
             + bias[c+j] + r[j];
}

// ---------------- fused flash attention (verified) ----------------
__global__ __launch_bounds__(256, 3) void k_flash(
    const bf16* __restrict__ qk, const bf16* __restrict__ VtAll,
    bf16* __restrict__ y)
{
  __shared__ alignas(16) bf16 sK[2][64*64];
  __shared__ alignas(16) bf16 sV[2][64*64];
  __shared__ alignas(16) bf16 sP[4][16*72];

  const int tid = threadIdx.x;
  const int wave = tid>>6, lane = tid&63;
  const int r16 = lane&15, kg = lane>>4;

  const int id = blockIdx.x;
  const int swz = (id&7)*240 + (id>>3);
  const int hh = swz/10, qt = swz - hh*10;
  const int b_ = hh/NHEAD, h_ = hh - b_*NHEAD;

  const int qrow = b_*SEQ + qt*64 + wave*16 + r16;
  v8s qf[2];
  qf[0] = *(const v8s*)(qk + (size_t)qrow*QKW + h_*DHEAD + kg*8);
  qf[1] = *(const v8s*)(qk + (size_t)qrow*QKW + h_*DHEAD + 32 + kg*8);

  auto stage = [&](int kt, int buf){
    #pragma unroll
    for (int i=0;i<2;i++){
      int chunk = i*256 + tid;
      int row = chunk>>3, ch = chunk&7;
      int sc = ch ^ (row&7);
      const bf16* gk = qk + (size_t)(b_*SEQ + kt*64 + row)*QKW
                          + C_DIM + h_*DHEAD + sc*8;
      const bf16* gv = VtAll + (size_t)(b_*C_DIM + h_*DHEAD + row)*NKV
                             + kt*64 + sc*8;
      __builtin_amdgcn_global_load_lds(
          (const __attribute__((address_space(1))) void*)gk,
          (__attribute__((address_space(3))) void*)((char*)&sK[buf][0] + i*4096 + wave*1024),
          16, 0, 0);
      __builtin_amdgcn_global_load_lds(
          (const __attribute__((address_space(1))) void*)gv,
          (__attribute__((address_space(3))) void*)((char*)&sV[buf][0] + i*4096 + wave*1024),
          16, 0, 0);
    }
  };

  float m_run = -1e30f, l_run = 0.f;
  v4f zero4 = {0.f,0.f,0.f,0.f};
  v4f o[4] = {zero4, zero4, zero4, zero4};

  stage(0, 0);
  for (int kt=0; kt<10; ++kt){
    __syncthreads();
    if (kt < 9) stage(kt+1, (kt+1)&1);
    const bf16* Kt = &sK[kt&1][0];
    const bf16* Vt = &sV[kt&1][0];

    v4f sfr[4] = {zero4, zero4, zero4, zero4};
    #pragma unroll
    for (int ks=0; ks<2; ++ks){
      #pragma unroll
      for (int m=0;m<4;m++){
        int key = m*16 + r16;
        v8s kf = *(const v8s*)(Kt + key*64 + (((ks*4+kg) ^ (key&7))*8));
        sfr[m] = __builtin_amdgcn_mfma_f32_16x16x32_bf16(kf, qf[ks], sfr[m], 0, 0, 0);
      }
    }

    if (kt == 9){
      #pragma unroll
      for (int m=0;m<4;m++)
        #pragma unroll
        for (int gg=0; gg<4; ++gg){
          int kb = 576 + m*16 + kg*4 + gg;
          if (kb >= SEQ) sfr[m][gg] = -1e30f;
        }
    }

    float tmax = -1e30f;
    #pragma unroll
    for (int m=0;m<4;m++)
      #pragma unroll
      for (int gg=0; gg<4; ++gg) tmax = fmaxf(tmax, sfr[m][gg]);
    tmax = fmaxf(tmax, __shfl_xor(tmax, 16));
    tmax = fmaxf(tmax, __shfl_xor(tmax, 32));
    float mn  = fmaxf(m_run, tmax);
    float scl = exp2f(m_run - mn);
    float ps  = 0.f;
    #pragma unroll
    for (int m=0;m<4;m++)
      #pragma unroll
      for (int gg=0; gg<4; ++gg){
        float pv = exp2f(sfr[m][gg] - mn);
        sfr[m][gg] = pv; ps += pv;
      }
    ps += __shfl_xor(ps, 16);
    ps += __shfl_xor(ps, 32);
    l_run = l_run*scl + ps;
    m_run = mn;
    #pragma unroll
    for (int mf=0; mf<4; ++mf) o[mf] *= scl;

    bf16* Pw = &sP[wave][0];
    #pragma unroll
    for (int m=0;m<4;m++){
      short4 w;
      w.x = f2s(sfr[m][0]); w.y = f2s(sfr[m][1]);
      w.z = f2s(sfr[m][2]); w.w = f2s(sfr[m][3]);
      *(short4*)(Pw + r16*72 + m*16 + kg*4) = w;
    }
    asm volatile("s_waitcnt lgkmcnt(0)" ::: "memory");
    v8s pb0 = *(const v8s*)(Pw + r16*72 + kg*8);
    v8s pb1 = *(const v8s*)(Pw + r16*72 + 32 + kg*8);
    #pragma unroll
    for (int mf=0; mf<4; ++mf){
      int d = mf*16 + r16;
      v8s v0 = *(const v8s*)(Vt + d*64 + ((kg     ^ (d&7))*8));
      v8s v1 = *(const v8s*)(Vt + d*64 + (((4+kg) ^ (d&7))*8));
      o[mf] = __builtin_amdgcn_mfma_f32_16x16x32_bf16(v0, pb0, o[mf], 0, 0, 0);
      o[mf] = __builtin_amdgcn_mfma_f32_16x16x32_bf16(v1, pb1, o[mf], 0, 0, 0);
    }
  }

  const int qg = qt*64 + wave*16 + r16;
  if (qg < SEQ){
    float inv = 1.f / l_run;
    #pragma unroll
    for (int mf=0; mf<4; ++mf){
      short4 w;
      w.x = f2s(o[mf][0]*inv); w.y = f2s(o[mf][1]*inv);
      w.z = f2s(o[mf][2]*inv); w.w = f2s(o[mf][3]*inv);
      *(short4*)(y + (size_t)(b_*SEQ + qg)*C_DIM + h_*DHEAD + mf*16 + kg*4) = w;
    }
  }
}

// ---------------- MFMA GEMM: C[M,N] = A[M,K] * BT[N,K]^T (128^2, verified) --
// EPI 0: qk (+bias, *QSCALE cols<768)   EPI 1: fc1 (+bias, fast GELU)
// EPI 5: Vt transposed scatter (+bias)  EPI 6: bf16 split-K partial (z chunk)
template<int EPI>
__global__ __launch_bounds__(256, 4) void gemm_bt(
    const bf16* __restrict__ A, int lda,
    const bf16* __restrict__ BT, int ldb,
    void* Cv, int ldc,
    const float* __restrict__ bias,
    const float* resid,
    int K)
{
  __shared__ alignas(16) bf16 sA[128*64];
  __shared__ alignas(16) bf16 sB[128*64];
  const int tid  = threadIdx.x;
  const int wave = tid>>6, lane = tid&63;
  const int wr = wave>>1, wc = wave&1;
  const int r16 = lane&15, kg = lane>>4;

  int nx = gridDim.x, nwg = nx*gridDim.y;
  int id = blockIdx.y*nx + blockIdx.x;
  int qq = nwg>>3, r8 = nwg&7, xcd = id&7, j = id>>3;
  int swz = (xcd<r8 ? xcd*(qq+1) : r8*(qq+1) + (xcd-r8)*qq) + j;
  int mt = swz / nx, nt = swz % nx;

  int kb = 0;
  if constexpr (EPI==6) kb = blockIdx.z * K;

  v4f acc[4][4];
  v4f zero4 = {0.f,0.f,0.f,0.f};
  #pragma unroll
  for (int m=0;m<4;m++)
    #pragma unroll
    for (int n=0;n<4;n++) acc[m][n] = zero4;

  const int mrow0 = mt*128, ncol0 = nt*128;

  for (int kt=0; kt<K; kt+=64){
    #pragma unroll
    for (int i=0;i<4;i++){
      int ci = wave*4 + i;
      int q  = ci*64 + lane;
      int rr = q>>3;
      int cc = (q&7)*8;
      const bf16* ga = A  + (size_t)(mrow0+rr)*lda + (kb+kt+cc);
      const bf16* gb = BT + (size_t)(ncol0+rr)*ldb + (kb+kt+cc);
      __builtin_amdgcn_global_load_lds(
          (const __attribute__((address_space(1))) void*)ga,
          (__attribute__((address_space(3))) void*)((char*)sA + ci*1024), 16, 0, 0);
      __builtin_amdgcn_global_load_lds(
          (const __attribute__((address_space(1))) void*)gb,
          (__attribute__((address_space(3))) void*)((char*)sB + ci*1024), 16, 0, 0);
    }
    __syncthreads();
    #pragma unroll
    for (int ks=0; ks<2; ks++){
      v8s av[4], bv[4];
      #pragma unroll
      for (int m=0;m<4;m++)
        av[m] = *(const v8s*)(sA + (wr*64 + m*16 + r16)*64 + ks*32 + kg*8);
      #pragma unroll
      for (int n=0;n<4;n++)
        bv[n] = *(const v8s*)(sB + (wc*64 + n*16 + r16)*64 + ks*32 + kg*8);
      #pragma unroll
      for (int m=0;m<4;m++)
        #pragma unroll
        for (int n=0;n<4;n++)
          acc[m][n] = __builtin_amdgcn_mfma_f32_16x16x32_bf16(av[m], bv[n], acc[m][n], 0, 0, 0);
    }
    __syncthreads();
  }

  #pragma unroll
  for (int m=0;m<4;m++){
    #pragma unroll
    for (int n=0;n<4;n++){
      int col = ncol0 + wc*64 + n*16 + r16;
      #pragma unroll
      for (int gg=0; gg<4; gg++){
        int row = mrow0 + wr*64 + m*16 + kg*4 + gg;
        float v = acc[m][n][gg];
        if constexpr (EPI==0){
          float oo = v + bias[col];
          if (col < C_DIM) oo *= QSCALE;
          ((bf16*)Cv)[(size_t)row*ldc + col] = f2b(oo);
        } else if constexpr (EPI==1){
          ((bf16*)Cv)[(size_t)row*ldc + col] = f2b(gelu_fast(v + bias[col]));
        } else if constexpr (EPI==5){
          int g = col;
          if (g < MREAL){
            int b = g / SEQ;
            int key = g - b*SEQ;
            ((bf16*)Cv)[((size_t)b*C_DIM + row)*NKV + key] = f2b(v + bias[row]);
          }
        } else { // EPI==6
          ((bf16*)Cv)[(size_t)blockIdx.z*MPAD*C_DIM + (size_t)row*ldc + col] = f2b(v);
        }
      }
    }
  }
}

// ---------------- launch ----------------

extern "C" void kernel_launch(void* const* d_in, const int* in_sizes, int n_in,
                              void* d_out, int out_size, void* d_ws, size_t ws_size,
                              hipStream_t stream)
{
  const float* x     = (const float*)d_in[0];
  const float* ln1g  = (const float*)d_in[1];
  const float* ln1b  = (const float*)d_in[2];
  const float* qkvw  = (const float*)d_in[3];
  const float* qkvb  = (const float*)d_in[4];
  const float* projw = (const float*)d_in[5];
  const float* projb = (const float*)d_in[6];
  const float* ln2g  = (const float*)d_in[7];
  const float* ln2b  = (const float*)d_in[8];
  const float* fc1w  = (const float*)d_in[9];
  const float* fc1b  = (const float*)d_in[10];
  const float* fc2w  = (const float*)d_in[11];
  const float* fc2b  = (const float*)d_in[12];
  float* out = (float*)d_out;

  char* p = (char*)d_ws;
  auto take = [&](size_t n){ char* r = p; p += (n + 255) & ~(size_t)255; return r; };
  bf16* qkvT = (bf16*)take((size_t)(3*C_DIM)*C_DIM*2);
  bf16* projT= (bf16*)take((size_t)C_DIM*C_DIM*2);
  bf16* fc1T = (bf16*)take((size_t)HID*C_DIM*2);
  bf16* fc2T = (bf16*)take((size_t)C_DIM*HID*2);
  bf16* xn   = (bf16*)take((size_t)MPAD*C_DIM*2);
  bf16* xn2  = (bf16*)take((size_t)MPAD*C_DIM*2);
  bf16* qk   = (bf16*)take((size_t)MPAD*QKW*2);   // later: split-K partials (2 x MPAD*C_DIM)
  bf16* y    = (bf16*)take((size_t)MPAD*C_DIM*2);
  bf16* h    = (bf16*)take((size_t)MPAD*HID*2);
  bf16* VtAll= (bf16*)take((size_t)(BATCH*C_DIM + 2*DHEAD)*NKV*2);
  bf16* P    = qk;  // partials overlay (qk dead after flash)

  k_transpose_all<<<1728, 256, 0, stream>>>(qkvw, projw, fc1w, fc2w,
                                            qkvT, projT, fc1T, fc2T);

  // LN1 -> xn
  k_layernorm<<<MPAD, 256, 0, stream>>>(x, ln1g, ln1b, xn);

  // qk = xn @ [Wq|Wk]^T + b
  gemm_bt<0><<<dim3(QKW/128, MPAD/128), 256, 0, stream>>>(
      xn, C_DIM, qkvT, C_DIM, qk, QKW, qkvb, nullptr, C_DIM);

  // VtAll = (xn @ Wv)^T + bv
  gemm_bt<5><<<dim3(MPAD/128, C_DIM/128), 256, 0, stream>>>(
      qkvT + (size_t)QKW*C_DIM, C_DIM, xn, C_DIM, VtAll, 0,
      qkvb + 2*C_DIM, nullptr, C_DIM);

  // fused flash attention -> y
  k_flash<<<1920, 256, 0, stream>>>(qk, VtAll, y);

  // proj split-K=2: partials, then fused reduce+LN2 (out, xn2)
  gemm_bt<6><<<dim3(C_DIM/128, MPAD/128, 2), 256, 0, stream>>>(
      y, C_DIM, projT, C_DIM, P, C_DIM, nullptr, nullptr, C_DIM/2);
  k_reduce2_ln<<<MPAD, 256, 0, stream>>>(P, projb, x, out, ln2g, ln2b, xn2);

  // h = gelu(xn2 @ fc1_w + b)
  gemm_bt<1><<<dim3(HID/128, MPAD/128), 256, 0, stream>>>(
      xn2, C_DIM, fc1T, C_DIM, h, HID, fc1b, nullptr, C_DIM);

  // fc2 split-K=2: partials, then out = p0+p1+fc2b+out
  gemm_bt<6><<<dim3(C_DIM/128, MPAD/128, 2), 256, 0, stream>>>(
      h, HID, fc2T, HID, P, C_DIM, nullptr, nullptr, HID/2);
  k_reduce2<<<(MREAL*C_DIM)/(256*8), 256, 0, stream>>>(P, fc2b, out, out);
}